// Round 1
// baseline (590.709 us; speedup 1.0000x reference)
//
#include <hip/hip_runtime.h>
#include <hip/hip_bf16.h>

// Problem constants (reference: IN_F=4096, OUT_F=4096, GROUP=128, x = (4,2048,4096))
#define K_DIM 4096
#define N_DIM 4096
#define M_DIM 8192
#define PACKROWS 512   // K_DIM / 8

typedef __bf16 bf16x8 __attribute__((ext_vector_type(8)));
typedef float floatx4 __attribute__((ext_vector_type(4)));

__device__ __forceinline__ unsigned short f2bf(float f) {
    union { float f; unsigned u; } v; v.f = f;
    unsigned u = v.u;
    return (unsigned short)((u + 0x7FFFu + ((u >> 16) & 1u)) >> 16);  // RNE
}

// ---------------- kernel 1: cast x (fp32 -> bf16), 8 elems/thread ----------------
__global__ __launch_bounds__(256) void cast_x_kernel(const float* __restrict__ x,
                                                     unsigned short* __restrict__ xb) {
    const int t = blockIdx.x * 256 + threadIdx.x;
    const int base = t * 8;
    float4 f0 = *(const float4*)(x + base);
    float4 f1 = *(const float4*)(x + base + 4);
    int4 o;
    o.x = (int)f2bf(f0.x) | ((int)f2bf(f0.y) << 16);
    o.y = (int)f2bf(f0.z) | ((int)f2bf(f0.w) << 16);
    o.z = (int)f2bf(f1.x) | ((int)f2bf(f1.y) << 16);
    o.w = (int)f2bf(f1.z) | ((int)f2bf(f1.w) << 16);
    *(int4*)(xb + base) = o;
}

// ------------- kernel 2: dequant int4 -> bf16 W^T (N_DIM x K_DIM, k contiguous) -------------
// W[k][n] = scales[k/128][n] * nib(k) - zeros[k/128][n];  one thread per packed word (p,n).
__global__ __launch_bounds__(256) void dequant_kernel(const int* __restrict__ qw,
                                                      const float* __restrict__ scales,
                                                      const float* __restrict__ zeros,
                                                      unsigned short* __restrict__ wt) {
    const int t = blockIdx.x * 256 + threadIdx.x;   // 512*4096 threads
    const int n = t & (N_DIM - 1);
    const int p = t >> 12;                          // 0..511  (k = p*8 + j)
    const int g = p >> 4;                           // group = (p*8)/128
    const unsigned w = (unsigned)qw[p * N_DIM + n];
    const float s = scales[g * N_DIM + n];
    const float z = zeros[g * N_DIM + n];
    unsigned short h[8];
#pragma unroll
    for (int j = 0; j < 8; ++j) {
        float q = (float)((w >> (4 * j)) & 0xFu);
        h[j] = f2bf(q * s - z);
    }
    int4 o;
    o.x = (int)h[0] | ((int)h[1] << 16);
    o.y = (int)h[2] | ((int)h[3] << 16);
    o.z = (int)h[4] | ((int)h[5] << 16);
    o.w = (int)h[6] | ((int)h[7] << 16);
    *(int4*)(wt + (size_t)n * K_DIM + p * 8) = o;
}

// ------------- kernel 3: bf16 GEMM, 128x128 tile, BK=64, global_load_lds staging -------------
// A = xb (M x K row-major), B = wt (N x K row-major, i.e. W^T), C = out (M x N fp32) + bias.
__global__ __launch_bounds__(256) void gemm_kernel(const unsigned short* __restrict__ A,
                                                   const unsigned short* __restrict__ B,
                                                   const float* __restrict__ bias,
                                                   float* __restrict__ C) {
    __shared__ unsigned short As[128 * 64];   // [row][k], lane-linear fill (no padding!)
    __shared__ unsigned short Bs[128 * 64];   // [n][k]

    const int tid = threadIdx.x;
    const int lane = tid & 63;
    const int wave = tid >> 6;
    const int tileM = blockIdx.y * 128;
    const int tileN = blockIdx.x * 128;

    // staging: thread t covers 8 contiguous bf16; 4 iters of 32 rows each
    const int srow = tid >> 3;          // 0..31
    const int scol = (tid & 7) * 8;     // 0,8,..,56
    const int aBase = (tileM + srow) * K_DIM + scol;
    const int bBase = (tileN + srow) * K_DIM + scol;
    const int ldsOff = tid * 8;         // elems into each 2048-elem chunk

    floatx4 acc[4][4];
#pragma unroll
    for (int i = 0; i < 4; ++i)
#pragma unroll
        for (int j = 0; j < 4; ++j) acc[i][j] = (floatx4){0.f, 0.f, 0.f, 0.f};

    const int m0 = (wave >> 1) * 64;    // wave's 64x64 subtile
    const int n0 = (wave & 1) * 64;
    const int frow = lane & 15;         // fragment row/col within 16
    const int fk = (lane >> 4) * 8;     // fragment k offset

    for (int k0 = 0; k0 < K_DIM; k0 += 64) {
#pragma unroll
        for (int j = 0; j < 4; ++j) {
            __builtin_amdgcn_global_load_lds(
                (__attribute__((address_space(1))) void*)(A + aBase + k0 + j * 32 * K_DIM),
                (__attribute__((address_space(3))) void*)(&As[j * 2048 + ldsOff]),
                16, 0, 0);
            __builtin_amdgcn_global_load_lds(
                (__attribute__((address_space(1))) void*)(B + bBase + k0 + j * 32 * K_DIM),
                (__attribute__((address_space(3))) void*)(&Bs[j * 2048 + ldsOff]),
                16, 0, 0);
        }
        __syncthreads();   // compiler emits s_waitcnt vmcnt(0) before s_barrier

#pragma unroll
        for (int kk = 0; kk < 64; kk += 32) {
            bf16x8 a[4], b[4];
#pragma unroll
            for (int i = 0; i < 4; ++i)
                a[i] = *(const bf16x8*)&As[(m0 + i * 16 + frow) * 64 + kk + fk];
#pragma unroll
            for (int i = 0; i < 4; ++i)
                b[i] = *(const bf16x8*)&Bs[(n0 + i * 16 + frow) * 64 + kk + fk];
#pragma unroll
            for (int mi = 0; mi < 4; ++mi)
#pragma unroll
                for (int ni = 0; ni < 4; ++ni)
                    acc[mi][ni] = __builtin_amdgcn_mfma_f32_16x16x32_bf16(
                        a[mi], b[ni], acc[mi][ni], 0, 0, 0);
        }
        __syncthreads();
    }

    // epilogue: C/D layout col = lane&15, row = (lane>>4)*4 + reg
    const int crow = (lane >> 4) * 4;
    const int ccol = lane & 15;
#pragma unroll
    for (int ni = 0; ni < 4; ++ni) {
        const int gcol = tileN + n0 + ni * 16 + ccol;
        const float bv = bias[gcol];
#pragma unroll
        for (int mi = 0; mi < 4; ++mi) {
            const int rbase = (tileM + m0 + mi * 16 + crow) * N_DIM + gcol;
#pragma unroll
            for (int r = 0; r < 4; ++r)
                C[rbase + r * N_DIM] = acc[mi][ni][r] + bv;
        }
    }
}

extern "C" void kernel_launch(void* const* d_in, const int* in_sizes, int n_in,
                              void* d_out, int out_size, void* d_ws, size_t ws_size,
                              hipStream_t stream) {
    (void)in_sizes; (void)n_in; (void)out_size; (void)ws_size;
    const float* x      = (const float*)d_in[0];
    const int*   qw     = (const int*)d_in[1];
    const float* scales = (const float*)d_in[2];
    const float* zeros  = (const float*)d_in[3];
    const float* bias   = (const float*)d_in[4];
    float* out = (float*)d_out;

    unsigned short* xb = (unsigned short*)d_ws;                      // 8192*4096 bf16 = 64 MiB
    unsigned short* wt = xb + (size_t)M_DIM * K_DIM;                 // 4096*4096 bf16 = 32 MiB

    // x -> bf16: 33554432 elems / 8 per thread / 256 per block = 16384 blocks
    hipLaunchKernelGGL(cast_x_kernel, dim3(16384), dim3(256), 0, stream, x, xb);
    // dequant: 512*4096 threads / 256 = 8192 blocks
    hipLaunchKernelGGL(dequant_kernel, dim3(8192), dim3(256), 0, stream, qw, scales, zeros, wt);
    // GEMM: 32 N-tiles x 64 M-tiles
    hipLaunchKernelGGL(gemm_kernel, dim3(32, 64), dim3(256), 0, stream, xb, wt, bias, out);
}

// Round 2
// 492.518 us; speedup vs baseline: 1.1994x; 1.1994x over previous
//
#include <hip/hip_runtime.h>
#include <hip/hip_bf16.h>

// Problem constants (reference: IN_F=4096, OUT_F=4096, GROUP=128, x = (4,2048,4096))
#define K_DIM 4096
#define N_DIM 4096
#define M_DIM 8192

typedef __bf16 bf16x8 __attribute__((ext_vector_type(8)));
typedef float floatx4 __attribute__((ext_vector_type(4)));

__device__ __forceinline__ unsigned short f2bf(float f) {
    union { float f; unsigned u; } v; v.f = f;
    unsigned u = v.u;
    return (unsigned short)((u + 0x7FFFu + ((u >> 16) & 1u)) >> 16);  // RNE
}

// ---------------- kernel 1: cast x (fp32 -> bf16), 8 elems/thread ----------------
__global__ __launch_bounds__(256) void cast_x_kernel(const float* __restrict__ x,
                                                     unsigned short* __restrict__ xb) {
    const int t = blockIdx.x * 256 + threadIdx.x;
    const int base = t * 8;
    float4 f0 = *(const float4*)(x + base);
    float4 f1 = *(const float4*)(x + base + 4);
    int4 o;
    o.x = (int)f2bf(f0.x) | ((int)f2bf(f0.y) << 16);
    o.y = (int)f2bf(f0.z) | ((int)f2bf(f0.w) << 16);
    o.z = (int)f2bf(f1.x) | ((int)f2bf(f1.y) << 16);
    o.w = (int)f2bf(f1.z) | ((int)f2bf(f1.w) << 16);
    *(int4*)(xb + base) = o;
}

// ------------- kernel 2: dequant int4 -> bf16 W^T (N x K, k contiguous), LDS transpose -------------
// Tile: 128 n x 64 k per block. Reads coalesced (consecutive n), writes coalesced
// (8 lanes cover one n-row's contiguous 128 B of k). LDS XOR-swizzled: 2-way max (free).
__global__ __launch_bounds__(256) void dequant_kernel(const int* __restrict__ qw,
                                                      const float* __restrict__ scales,
                                                      const float* __restrict__ zeros,
                                                      unsigned short* __restrict__ wt) {
    __shared__ int4 lds[128 * 8];                   // [n][chunk], 16 KB
    const int tid = threadIdx.x;
    const int nb = (blockIdx.x & 31) * 128;         // n-block base
    const int kb = blockIdx.x >> 5;                 // 0..63, k0 = kb*64
    const int p0 = kb * 8;                          // packed-row base (8 words = 64 k)
    const int g = kb >> 1;                          // quant group (uniform per block)

#pragma unroll
    for (int it = 0; it < 4; ++it) {
        const int w = tid + it * 256;               // 0..1023
        const int p = w >> 7;                       // 0..7
        const int n = w & 127;
        const unsigned word = (unsigned)qw[(p0 + p) * N_DIM + nb + n];
        const float s = scales[g * N_DIM + nb + n];
        const float z = zeros[g * N_DIM + nb + n];
        unsigned short h[8];
#pragma unroll
        for (int j = 0; j < 8; ++j) {
            float q = (float)((word >> (4 * j)) & 0xFu);
            h[j] = f2bf(q * s - z);
        }
        int4 o;
        o.x = (int)h[0] | ((int)h[1] << 16);
        o.y = (int)h[2] | ((int)h[3] << 16);
        o.z = (int)h[4] | ((int)h[5] << 16);
        o.w = (int)h[6] | ((int)h[7] << 16);
        lds[n * 8 + (p ^ (n & 7))] = o;             // swizzled chunk
    }
    __syncthreads();

#pragma unroll
    for (int it = 0; it < 4; ++it) {
        const int r = (tid >> 3) + it * 32;         // n-row 0..127
        const int oc = tid & 7;                     // k-chunk 0..7
        int4 v = lds[r * 8 + (oc ^ (r & 7))];
        *(int4*)(wt + (size_t)(nb + r) * K_DIM + kb * 64 + oc * 8) = v;
    }
}

// ------------- kernel 3: bf16 GEMM, 128x128 tile, BK=64, global_load_lds staging -------------
// A = xb (M x K row-major), B = wt (N x K row-major), C = out (M x N fp32) + bias.
// LDS chunk-XOR swizzle: LDS[row][c] holds global chunk (c ^ (row&7)); applied on the
// global source address (permutes 16B chunks within each row's 128B — stays coalesced)
// because global_load_lds forces a lane-linear LDS destination. Fragment reads un-swizzle,
// spreading each 16-lane phase across all 8 bank quads (2 lanes/quad = conflict-free).
__global__ __launch_bounds__(256) void gemm_kernel(const unsigned short* __restrict__ A,
                                                   const unsigned short* __restrict__ B,
                                                   const float* __restrict__ bias,
                                                   float* __restrict__ C) {
    __shared__ unsigned short As[128 * 64];
    __shared__ unsigned short Bs[128 * 64];

    const int tid = threadIdx.x;
    const int lane = tid & 63;
    const int wave = tid >> 6;
    const int tileM = blockIdx.y * 128;
    const int tileN = blockIdx.x * 128;

    // staging: thread t covers one 16B chunk; source chunk swizzled by row&7
    const int srow = tid >> 3;                      // 0..31
    const int scol = ((tid & 7) ^ (srow & 7)) * 8;  // swizzled source chunk
    const int aBase = (tileM + srow) * K_DIM + scol;
    const int bBase = (tileN + srow) * K_DIM + scol;
    const int ldsOff = tid * 8;                     // lane-linear dest

    floatx4 acc[4][4];
#pragma unroll
    for (int i = 0; i < 4; ++i)
#pragma unroll
        for (int j = 0; j < 4; ++j) acc[i][j] = (floatx4){0.f, 0.f, 0.f, 0.f};

    const int m0 = (wave >> 1) * 64;                // wave's 64x64 subtile
    const int n0 = (wave & 1) * 64;
    const int frow = lane & 15;
    const int fkq = lane >> 4;                      // k-chunk quarter index
    const int sw = lane & 7;                        // row&7 for this lane's rows

    for (int k0 = 0; k0 < K_DIM; k0 += 64) {
#pragma unroll
        for (int j = 0; j < 4; ++j) {
            __builtin_amdgcn_global_load_lds(
                (__attribute__((address_space(1))) void*)(A + aBase + k0 + j * 32 * K_DIM),
                (__attribute__((address_space(3))) void*)(&As[j * 2048 + ldsOff]),
                16, 0, 0);
            __builtin_amdgcn_global_load_lds(
                (__attribute__((address_space(1))) void*)(B + bBase + k0 + j * 32 * K_DIM),
                (__attribute__((address_space(3))) void*)(&Bs[j * 2048 + ldsOff]),
                16, 0, 0);
        }
        __syncthreads();

#pragma unroll
        for (int kk = 0; kk < 64; kk += 32) {
            const int jc = (kk >> 3) + fkq;         // needed global chunk
            const int ch = (jc ^ sw) << 3;          // un-swizzled LDS elem offset
            bf16x8 a[4], b[4];
#pragma unroll
            for (int i = 0; i < 4; ++i)
                a[i] = *(const bf16x8*)&As[(m0 + i * 16 + frow) * 64 + ch];
#pragma unroll
            for (int i = 0; i < 4; ++i)
                b[i] = *(const bf16x8*)&Bs[(n0 + i * 16 + frow) * 64 + ch];
#pragma unroll
            for (int mi = 0; mi < 4; ++mi)
#pragma unroll
                for (int ni = 0; ni < 4; ++ni)
                    acc[mi][ni] = __builtin_amdgcn_mfma_f32_16x16x32_bf16(
                        a[mi], b[ni], acc[mi][ni], 0, 0, 0);
        }
        __syncthreads();
    }

    // epilogue: C/D layout col = lane&15, row = (lane>>4)*4 + reg
    const int crow = (lane >> 4) * 4;
    const int ccol = lane & 15;
#pragma unroll
    for (int ni = 0; ni < 4; ++ni) {
        const int gcol = tileN + n0 + ni * 16 + ccol;
        const float bv = bias[gcol];
#pragma unroll
        for (int mi = 0; mi < 4; ++mi) {
            const int rbase = (tileM + m0 + mi * 16 + crow) * N_DIM + gcol;
#pragma unroll
            for (int r = 0; r < 4; ++r)
                C[rbase + r * N_DIM] = acc[mi][ni][r] + bv;
        }
    }
}

extern "C" void kernel_launch(void* const* d_in, const int* in_sizes, int n_in,
                              void* d_out, int out_size, void* d_ws, size_t ws_size,
                              hipStream_t stream) {
    (void)in_sizes; (void)n_in; (void)out_size; (void)ws_size;
    const float* x      = (const float*)d_in[0];
    const int*   qw     = (const int*)d_in[1];
    const float* scales = (const float*)d_in[2];
    const float* zeros  = (const float*)d_in[3];
    const float* bias   = (const float*)d_in[4];
    float* out = (float*)d_out;

    unsigned short* xb = (unsigned short*)d_ws;                      // 8192*4096 bf16 = 64 MiB
    unsigned short* wt = xb + (size_t)M_DIM * K_DIM;                 // 4096*4096 bf16 = 32 MiB

    hipLaunchKernelGGL(cast_x_kernel, dim3(16384), dim3(256), 0, stream, x, xb);
    hipLaunchKernelGGL(dequant_kernel, dim3(2048), dim3(256), 0, stream, qw, scales, zeros, wt);
    hipLaunchKernelGGL(gemm_kernel, dim3(32, 64), dim3(256), 0, stream, xb, wt, bias, out);
}